// Round 2
// baseline (308.424 us; speedup 1.0000x reference)
//
#include <hip/hip_runtime.h>

typedef __attribute__((ext_vector_type(8))) short short8;
typedef __attribute__((ext_vector_type(4))) float floatx4;

// fp32 -> bf16 bits, round-to-nearest-even (finite inputs only)
__device__ inline short to_bf16s(float f) {
    unsigned u = __builtin_bit_cast(unsigned, f);
    unsigned r = u + 0x7FFFu + ((u >> 16) & 1u);
    return (short)(r >> 16);
}
__device__ inline short to_bf16s(short s) { return s; }

// ---------------------------------------------------------------------------
// 8-element k-contiguous fragment loader -> bf16 bits
// ---------------------------------------------------------------------------
template <typename T> struct Ld8;
template <> struct Ld8<short> {
    static __device__ inline short8 load(const short* p) { return *(const short8*)p; }
};
template <> struct Ld8<float> {
    static __device__ inline short8 load(const float* p) {
        float4 f0 = *(const float4*)p;
        float4 f1 = *(const float4*)(p + 4);
        short8 r;
        r[0] = to_bf16s(f0.x); r[1] = to_bf16s(f0.y);
        r[2] = to_bf16s(f0.z); r[3] = to_bf16s(f0.w);
        r[4] = to_bf16s(f1.x); r[5] = to_bf16s(f1.y);
        r[6] = to_bf16s(f1.z); r[7] = to_bf16s(f1.w);
        return r;
    }
};

__device__ inline void storeC(short* p, float x) { *p = to_bf16s(x); }
__device__ inline void storeC(float* p, float x) { *p = x; }

// ---------------------------------------------------------------------------
// Tile transpose with bf16 conversion: in (R x C, type T) -> out (C x R, bf16)
// Grid: dim3(C/32, R/32), block 256.
// ---------------------------------------------------------------------------
template <typename T>
__global__ __launch_bounds__(256) void transpose_to_bf16(const T* __restrict__ in,
                                                         short* __restrict__ out,
                                                         int R, int C) {
    __shared__ short tile[32][33];
    int bx = blockIdx.x * 32;  // col base in input
    int by = blockIdx.y * 32;  // row base in input
    int tx = threadIdx.x & 31;
    int ty = threadIdx.x >> 5;  // 0..7
    #pragma unroll
    for (int i = ty; i < 32; i += 8) tile[i][tx] = to_bf16s(in[(size_t)(by + i) * C + bx + tx]);
    __syncthreads();
    #pragma unroll
    for (int i = ty; i < 32; i += 8) out[(size_t)(bx + i) * R + by + tx] = tile[tx][i];
}

// ---------------------------------------------------------------------------
// Row-sum of fp32 adjacency -> 1 / max(sum, 1).  Grid: 2048 blocks, 256 thr.
// ---------------------------------------------------------------------------
__global__ __launch_bounds__(256) void rowsum_invdeg(const float* __restrict__ adj,
                                                     float* __restrict__ invdeg,
                                                     int Ncols) {
    int row = blockIdx.x;
    const float* p = adj + (size_t)row * Ncols;
    float s = 0.f;
    for (int c = threadIdx.x; c < Ncols; c += 256) s += p[c];
    __shared__ float red[256];
    red[threadIdx.x] = s;
    __syncthreads();
    for (int st = 128; st > 0; st >>= 1) {
        if (threadIdx.x < st) red[threadIdx.x] += red[threadIdx.x + st];
        __syncthreads();
    }
    if (threadIdx.x == 0) {
        float d = red[0];
        d = d < 1.f ? 1.f : d;
        invdeg[row] = 1.f / d;
    }
}

// ---------------------------------------------------------------------------
// BT GEMM:  C[M,N] = sum over segments s of  A_s[M,K_s] @ B_s[N,K_s]^T
// A/B element types TA/TB in {float, short(bf16 bits)}; converted to bf16 at
// staging. 64x64 tile, BK=64, 256 thr = 4 waves 2x2, each wave 32x32 via 2x2
// of v_mfma_f32_16x16x32_bf16. Double-buffered LDS + register prefetch.
// Epilogue: +bias[col] (fp32), *rowscale[row] (fp32, pre-remap row), relu,
// row remap (0: identity, 1: b*2048+n -> n*4+b, 2: n*4+b -> b*2048+n).
// ---------------------------------------------------------------------------
#define LDSTR 72           // 64 + 8 bf16 pad: conflict-free ds_read_b128
#define TILE_ELEMS (64 * LDSTR)

template <typename TA, typename TB, typename TC>
__global__ __launch_bounds__(256) void gemm_bt(
    const TA* __restrict__ A0, const TA* __restrict__ A1,
    const TB* __restrict__ B0, const TB* __restrict__ B1,
    int lda, int ldb, int k0tiles, int k1tiles,
    const float* __restrict__ bias, const float* __restrict__ rowscale,
    TC* __restrict__ C, int ldc, int relu, int rowmap) {
    __shared__ __align__(16) short lds[4 * TILE_ELEMS];  // 2 buffers x (As + Bs)

    int tid = threadIdx.x;
    int blockM = blockIdx.x * 64;
    int blockN = blockIdx.y * 64;
    int nIters = k0tiles + k1tiles;

    int srow = tid >> 3;         // 0..31 (second half: +32)
    int scol = (tid & 7) * 8;    // 0..56, 8-element chunks

    auto baseA = [&](int it) -> const TA* {
        return (it < k0tiles) ? A0 + (size_t)blockM * lda + it * 64
                              : A1 + (size_t)blockM * lda + (it - k0tiles) * 64;
    };
    auto baseB = [&](int it) -> const TB* {
        return (it < k0tiles) ? B0 + (size_t)blockN * ldb + it * 64
                              : B1 + (size_t)blockN * ldb + (it - k0tiles) * 64;
    };

    // prefetch k-tile 0 into registers (already converted to bf16 bits)
    short8 ra0, ra1, rb0, rb1;
    {
        const TA* Ab = baseA(0);
        const TB* Bb = baseB(0);
        ra0 = Ld8<TA>::load(Ab + (size_t)srow * lda + scol);
        ra1 = Ld8<TA>::load(Ab + (size_t)(srow + 32) * lda + scol);
        rb0 = Ld8<TB>::load(Bb + (size_t)srow * ldb + scol);
        rb1 = Ld8<TB>::load(Bb + (size_t)(srow + 32) * ldb + scol);
    }

    floatx4 acc[2][2];
    #pragma unroll
    for (int i = 0; i < 2; ++i)
        #pragma unroll
        for (int j = 0; j < 2; ++j)
            #pragma unroll
            for (int r = 0; r < 4; ++r) acc[i][j][r] = 0.f;

    int lane = tid & 63;
    int w = tid >> 6;
    int wr = w >> 1, wc = w & 1;
    int quad = lane >> 4, l15 = lane & 15;

    for (int it = 0; it < nIters; ++it) {
        short* As = lds + (it & 1) * (2 * TILE_ELEMS);
        short* Bs = As + TILE_ELEMS;
        *(short8*)(As + srow * LDSTR + scol) = ra0;
        *(short8*)(As + (srow + 32) * LDSTR + scol) = ra1;
        *(short8*)(Bs + srow * LDSTR + scol) = rb0;
        *(short8*)(Bs + (srow + 32) * LDSTR + scol) = rb1;
        __syncthreads();
        if (it + 1 < nIters) {  // prefetch next k-tile; overlaps MFMAs below
            const TA* Ab = baseA(it + 1);
            const TB* Bb = baseB(it + 1);
            ra0 = Ld8<TA>::load(Ab + (size_t)srow * lda + scol);
            ra1 = Ld8<TA>::load(Ab + (size_t)(srow + 32) * lda + scol);
            rb0 = Ld8<TB>::load(Bb + (size_t)srow * ldb + scol);
            rb1 = Ld8<TB>::load(Bb + (size_t)(srow + 32) * ldb + scol);
        }
        const short* Arow = As + (wr * 32 + l15) * LDSTR;
        const short* Brow = Bs + (wc * 32 + l15) * LDSTR;
        #pragma unroll
        for (int ks = 0; ks < 2; ++ks) {
            int kof = ks * 32 + quad * 8;
            short8 a0 = *(const short8*)(Arow + kof);
            short8 a1 = *(const short8*)(Arow + 16 * LDSTR + kof);
            short8 b0 = *(const short8*)(Brow + kof);
            short8 b1 = *(const short8*)(Brow + 16 * LDSTR + kof);
            acc[0][0] = __builtin_amdgcn_mfma_f32_16x16x32_bf16(a0, b0, acc[0][0], 0, 0, 0);
            acc[0][1] = __builtin_amdgcn_mfma_f32_16x16x32_bf16(a0, b1, acc[0][1], 0, 0, 0);
            acc[1][0] = __builtin_amdgcn_mfma_f32_16x16x32_bf16(a1, b0, acc[1][0], 0, 0, 0);
            acc[1][1] = __builtin_amdgcn_mfma_f32_16x16x32_bf16(a1, b1, acc[1][1], 0, 0, 0);
        }
    }

    // epilogue: C/D layout col=lane&15, row=quad*4+reg (m89-verified)
    #pragma unroll
    for (int ti = 0; ti < 2; ++ti) {
        #pragma unroll
        for (int tj = 0; tj < 2; ++tj) {
            int col = blockN + wc * 32 + tj * 16 + l15;
            float bv = bias ? bias[col] : 0.f;
            int row0 = blockM + wr * 32 + ti * 16 + quad * 4;
            #pragma unroll
            for (int r = 0; r < 4; ++r) {
                int m = row0 + r;
                float x = acc[ti][tj][r] + bv;
                if (rowscale) x *= rowscale[m];
                if (relu) x = x > 0.f ? x : 0.f;
                int orow = (rowmap == 0) ? m
                         : (rowmap == 1) ? (((m & 2047) << 2) | (m >> 11))
                                         : (((m & 3) << 11) | (m >> 2));
                storeC(&C[(size_t)orow * ldc + col], x);
            }
        }
    }
}

// ---------------------------------------------------------------------------
// Launch
// ---------------------------------------------------------------------------
extern "C" void kernel_launch(void* const* d_in, const int* in_sizes, int n_in,
                              void* d_out, int out_size, void* d_ws, size_t ws_size,
                              hipStream_t stream) {
    const float* x      = (const float*)d_in[0];
    const float* adj    = (const float*)d_in[1];
    const float* W_mlp2 = (const float*)d_in[2];
    const float* b_mlp2 = (const float*)d_in[3];
    const float* Wr1    = (const float*)d_in[4];
    const float* Wo1    = (const float*)d_in[5];
    const float* b1     = (const float*)d_in[6];
    const float* Wr2    = (const float*)d_in[7];
    const float* Wo2    = (const float*)d_in[8];
    const float* b2     = (const float*)d_in[9];
    const float* Wr3    = (const float*)d_in[10];
    const float* Wo3    = (const float*)d_in[11];
    const float* b3     = (const float*)d_in[12];
    const float* W_mlp1 = (const float*)d_in[13];
    const float* b_mlp1 = (const float*)d_in[14];
    float* out = (float*)d_out;

    char* ws = (char*)d_ws;
    size_t off = 0;
    auto alloc = [&](size_t bytes) -> char* {
        char* p = ws + off;
        off = (off + bytes + 255) & ~(size_t)255;
        return p;
    };
    short* W2T = (short*)alloc(128 * 1536 * 2);   // W_mlp2^T  (128 x 1536) bf16
    short* W1T = (short*)alloc(1536 * 128 * 2);   // W_mlp1^T  (1536 x 128) bf16
    short* WrT[3]; short* WoT[3];
    for (int l = 0; l < 3; ++l) {
        WrT[l] = (short*)alloc(128 * 128 * 2);
        WoT[l] = (short*)alloc(128 * 128 * 2);
    }
    float* invdeg = (float*)alloc(2048 * 4);
    short* Hp0 = (short*)alloc(2048 * 512 * 2);   // H in layout [n][(b,d)] bf16
    short* Hp1 = (short*)alloc(2048 * 512 * 2);
    short* Hp2 = (short*)alloc(2048 * 512 * 2);
    short* Hp3 = (short*)alloc(2048 * 512 * 2);
    short* HT  = (short*)alloc(512 * 2048 * 2);   // Hp^T (512 x 2048), reused
    short* AGG = (short*)alloc(2048 * 512 * 2);   // invdeg * (adj @ Hp), reused

    dim3 blk(256);

    // weight transposes + fp32->bf16 (GEMM B-operand is [N][K], k-contiguous)
    transpose_to_bf16<float><<<dim3(4, 48), blk, 0, stream>>>(W_mlp2, W2T, 1536, 128);
    transpose_to_bf16<float><<<dim3(48, 4), blk, 0, stream>>>(W_mlp1, W1T, 128, 1536);
    transpose_to_bf16<float><<<dim3(4, 4), blk, 0, stream>>>(Wr1, WrT[0], 128, 128);
    transpose_to_bf16<float><<<dim3(4, 4), blk, 0, stream>>>(Wo1, WoT[0], 128, 128);
    transpose_to_bf16<float><<<dim3(4, 4), blk, 0, stream>>>(Wr2, WrT[1], 128, 128);
    transpose_to_bf16<float><<<dim3(4, 4), blk, 0, stream>>>(Wo2, WoT[1], 128, 128);
    transpose_to_bf16<float><<<dim3(4, 4), blk, 0, stream>>>(Wr3, WrT[2], 128, 128);
    transpose_to_bf16<float><<<dim3(4, 4), blk, 0, stream>>>(Wo3, WoT[2], 128, 128);

    rowsum_invdeg<<<2048, blk, 0, stream>>>(adj, invdeg, 2048);

    // mlp2: Hp0[n*4+b] = x[b*2048+n] @ W_mlp2 + b_mlp2   (M=8192,K=1536,N=128)
    gemm_bt<float, short, short><<<dim3(128, 2), blk, 0, stream>>>(
        x, nullptr, W2T, nullptr, 1536, 1536, 24, 0,
        b_mlp2, nullptr, Hp0, 128, 0, 1);

    const float* biases[3] = {b1, b2, b3};
    short* Houts[3] = {Hp1, Hp2, Hp3};
    short* Hin = Hp0;
    for (int l = 0; l < 3; ++l) {
        // HT = Hp^T  (2048x512 -> 512x2048)
        transpose_to_bf16<short><<<dim3(16, 64), blk, 0, stream>>>(Hin, HT, 2048, 512);
        // AGG = invdeg * (adj @ Hp)   (M=2048,K=2048,N=512)
        gemm_bt<float, short, short><<<dim3(32, 8), blk, 0, stream>>>(
            adj, nullptr, HT, nullptr, 2048, 2048, 32, 0,
            nullptr, invdeg, AGG, 512, 0, 0);
        // H' = AGG@Wr + Hp@Wo + b (+relu layers 0,1)   (M=8192,K=128+128,N=128)
        gemm_bt<short, short, short><<<dim3(128, 2), blk, 0, stream>>>(
            AGG, Hin, WrT[l], WoT[l], 128, 128, 2, 2,
            biases[l], nullptr, Houts[l], 128, (l < 2) ? 1 : 0, 0);
        Hin = Houts[l];
    }

    // mlp1: out[b*2048+n] = Hp3[n*4+b] @ W_mlp1 + b_mlp1  (M=8192,K=128,N=1536)
    gemm_bt<short, short, float><<<dim3(128, 24), blk, 0, stream>>>(
        Hp3, nullptr, W1T, nullptr, 128, 128, 2, 0,
        b_mlp1, nullptr, out, 1536, 0, 2);
}

// Round 3
// 248.329 us; speedup vs baseline: 1.2420x; 1.2420x over previous
//
#include <hip/hip_runtime.h>

typedef __attribute__((ext_vector_type(8))) short short8;
typedef __attribute__((ext_vector_type(4))) float floatx4;

// fp32 -> bf16 bits, round-to-nearest-even (finite inputs only)
__device__ inline short to_bf16s(float f) {
    unsigned u = __builtin_bit_cast(unsigned, f);
    unsigned r = u + 0x7FFFu + ((u >> 16) & 1u);
    return (short)(r >> 16);
}

// async 16B global -> LDS DMA (wave-uniform base + lane*16; lane-ordered layout)
__device__ inline void dma16(const short* g, short* l) {
    __builtin_amdgcn_global_load_lds(
        (const __attribute__((address_space(1))) unsigned int*)(const void*)g,
        (__attribute__((address_space(3))) unsigned int*)(void*)l,
        16, 0, 0);
}

// ---------------------------------------------------------------------------
// 8-element k-contiguous fragment loader -> bf16 bits
// ---------------------------------------------------------------------------
template <typename T> struct Ld8;
template <> struct Ld8<short> {
    static __device__ inline short8 load(const short* p) { return *(const short8*)p; }
};
template <> struct Ld8<float> {
    static __device__ inline short8 load(const float* p) {
        float4 f0 = *(const float4*)p;
        float4 f1 = *(const float4*)(p + 4);
        short8 r;
        r[0] = to_bf16s(f0.x); r[1] = to_bf16s(f0.y);
        r[2] = to_bf16s(f0.z); r[3] = to_bf16s(f0.w);
        r[4] = to_bf16s(f1.x); r[5] = to_bf16s(f1.y);
        r[6] = to_bf16s(f1.z); r[7] = to_bf16s(f1.w);
        return r;
    }
};

// ---------------------------------------------------------------------------
// prep: blocks [0,2048): adjS[row] = adj[row] * (1/max(rowsum,1)), fp32->bf16.
//       blocks [2048,2528): weight transposes into W2T, W1T, BigB[3].
// BigB_l [128][640]: cols kc*128+k = Wr_l[k][j] (kc=0..3), cols 512+k = Wo_l[k][j].
// ---------------------------------------------------------------------------
struct PrepArgs {
    const float* adj;
    const float* W2; const float* W1;
    const float* Wr0; const float* Wo0;
    const float* Wr1; const float* Wo1;
    const float* Wr2; const float* Wo2;
    short* adjS; short* W2T; short* W1T;
    short* BigB0; short* BigB1; short* BigB2;
};

__global__ __launch_bounds__(256) void prep(PrepArgs p) {
    int bid = blockIdx.x;
    if (bid < 2048) {
        const float* src = p.adj + (size_t)bid * 2048;
        float s = 0.f;
        for (int c = threadIdx.x; c < 2048; c += 256) s += src[c];
        __shared__ float red[256];
        red[threadIdx.x] = s;
        __syncthreads();
        for (int st = 128; st > 0; st >>= 1) {
            if (threadIdx.x < st) red[threadIdx.x] += red[threadIdx.x + st];
            __syncthreads();
        }
        float d = red[0];
        d = d < 1.f ? 1.f : d;
        float inv = 1.f / d;
        short* dst = p.adjS + (size_t)bid * 2048;
        for (int c = threadIdx.x; c < 2048; c += 256) dst[c] = to_bf16s(src[c] * inv);
        return;
    }
    int t = bid - 2048;
    __shared__ short tile[32][33];
    int tx = threadIdx.x & 31, ty0 = threadIdx.x >> 5;
    const float* in; int C_; int bx, by;
    short* outp; int outld, copies, copystride, outofs;
    if (t < 192) {  // W2 [1536][128] -> W2T [128][1536]
        bx = (t & 3) * 32; by = (t >> 2) * 32; in = p.W2; C_ = 128;
        outp = p.W2T; outld = 1536; copies = 1; copystride = 0; outofs = 0;
    } else if (t < 384) {  // W1 [128][1536] -> W1T [1536][128]
        int u = t - 192; bx = (u % 48) * 32; by = (u / 48) * 32; in = p.W1; C_ = 1536;
        outp = p.W1T; outld = 128; copies = 1; copystride = 0; outofs = 0;
    } else {  // Wr/Wo [128][128] -> BigB_l
        int u = t - 384; int l = u / 32; int v = u % 32;
        const float* Wr[3] = {p.Wr0, p.Wr1, p.Wr2};
        const float* Wo[3] = {p.Wo0, p.Wo1, p.Wo2};
        short* BB[3] = {p.BigB0, p.BigB1, p.BigB2};
        outp = BB[l]; outld = 640; C_ = 128;
        if (v < 16) { in = Wr[l]; bx = (v & 3) * 32; by = (v >> 2) * 32;
                      copies = 4; copystride = 128; outofs = 0; }
        else { v -= 16; in = Wo[l]; bx = (v & 3) * 32; by = (v >> 2) * 32;
               copies = 1; copystride = 0; outofs = 512; }
    }
    for (int i = ty0; i < 32; i += 8)
        tile[i][tx] = to_bf16s(in[(size_t)(by + i) * C_ + bx + tx]);
    __syncthreads();
    for (int i = ty0; i < 32; i += 8) {
        short v = tile[tx][i];
        for (int c = 0; c < copies; ++c)
            outp[(size_t)(bx + i) * outld + (by + tx) + outofs + c * copystride] = v;
    }
}

// ---------------------------------------------------------------------------
// transposeHp: HT[b*128+d][n] = big[(n*4+b)][512+d].  grid (4, 64, 4).
// ---------------------------------------------------------------------------
__global__ __launch_bounds__(256) void transposeHp(const short* __restrict__ big,
                                                   short* __restrict__ HT) {
    __shared__ short tile[32][33];
    int bx = blockIdx.x * 32;  // d base
    int by = blockIdx.y * 32;  // n base
    int b = blockIdx.z;
    int tx = threadIdx.x & 31, ty0 = threadIdx.x >> 5;
    for (int i = ty0; i < 32; i += 8)
        tile[i][tx] = big[(size_t)((by + i) * 4 + b) * 640 + 512 + bx + tx];
    __syncthreads();
    for (int i = ty0; i < 32; i += 8)
        HT[(size_t)(b * 128 + bx + i) * 2048 + by + tx] = tile[tx][i];
}

// ---------------------------------------------------------------------------
// gemm64: C = A[M,K] @ B[N,K]^T, 64x64 tile, BK=64, reg-prefetch dbuf LDS.
// A: float or bf16(short); B bf16. Epilogue: +bias, relu, rowmap, colofs.
// rowmap: 0 identity, 1: (b*2048+n) -> n*4+b. Writes bf16.
// ---------------------------------------------------------------------------
#define LDSTR 72
#define TILE_ELEMS (64 * LDSTR)

template <typename TA>
__global__ __launch_bounds__(256) void gemm64(
    const TA* __restrict__ A, int lda,
    const short* __restrict__ B, int ldb, int kTiles,
    const float* __restrict__ bias,
    short* __restrict__ C, int ldc, int colofs, int relu, int rowmap) {
    __shared__ __align__(16) short lds[4 * TILE_ELEMS];

    int tid = threadIdx.x;
    int blockM = blockIdx.x * 64;
    int blockN = blockIdx.y * 64;

    int srow = tid >> 3;
    int scol = (tid & 7) * 8;

    const TA* Abase = A + (size_t)blockM * lda;
    const short* Bbase = B + (size_t)blockN * ldb;

    short8 ra0, ra1, rb0, rb1;
    ra0 = Ld8<TA>::load(Abase + (size_t)srow * lda + scol);
    ra1 = Ld8<TA>::load(Abase + (size_t)(srow + 32) * lda + scol);
    rb0 = Ld8<short>::load(Bbase + (size_t)srow * ldb + scol);
    rb1 = Ld8<short>::load(Bbase + (size_t)(srow + 32) * ldb + scol);

    floatx4 acc[2][2];
    #pragma unroll
    for (int i = 0; i < 2; ++i)
        #pragma unroll
        for (int j = 0; j < 2; ++j)
            #pragma unroll
            for (int r = 0; r < 4; ++r) acc[i][j][r] = 0.f;

    int lane = tid & 63;
    int w = tid >> 6;
    int wr = w >> 1, wc = w & 1;
    int quad = lane >> 4, l15 = lane & 15;

    for (int it = 0; it < kTiles; ++it) {
        short* As = lds + (it & 1) * (2 * TILE_ELEMS);
        short* Bs = As + TILE_ELEMS;
        *(short8*)(As + srow * LDSTR + scol) = ra0;
        *(short8*)(As + (srow + 32) * LDSTR + scol) = ra1;
        *(short8*)(Bs + srow * LDSTR + scol) = rb0;
        *(short8*)(Bs + (srow + 32) * LDSTR + scol) = rb1;
        __syncthreads();
        if (it + 1 < kTiles) {
            int ko = (it + 1) * 64;
            ra0 = Ld8<TA>::load(Abase + (size_t)srow * lda + ko + scol);
            ra1 = Ld8<TA>::load(Abase + (size_t)(srow + 32) * lda + ko + scol);
            rb0 = Ld8<short>::load(Bbase + (size_t)srow * ldb + ko + scol);
            rb1 = Ld8<short>::load(Bbase + (size_t)(srow + 32) * ldb + ko + scol);
        }
        const short* Arow = As + (wr * 32 + l15) * LDSTR;
        const short* Brow = Bs + (wc * 32 + l15) * LDSTR;
        #pragma unroll
        for (int ks = 0; ks < 2; ++ks) {
            int kof = ks * 32 + quad * 8;
            short8 a0 = *(const short8*)(Arow + kof);
            short8 a1 = *(const short8*)(Arow + 16 * LDSTR + kof);
            short8 b0 = *(const short8*)(Brow + kof);
            short8 b1 = *(const short8*)(Brow + 16 * LDSTR + kof);
            acc[0][0] = __builtin_amdgcn_mfma_f32_16x16x32_bf16(a0, b0, acc[0][0], 0, 0, 0);
            acc[0][1] = __builtin_amdgcn_mfma_f32_16x16x32_bf16(a0, b1, acc[0][1], 0, 0, 0);
            acc[1][0] = __builtin_amdgcn_mfma_f32_16x16x32_bf16(a1, b0, acc[1][0], 0, 0, 0);
            acc[1][1] = __builtin_amdgcn_mfma_f32_16x16x32_bf16(a1, b1, acc[1][1], 0, 0, 0);
        }
        __syncthreads();
    }

    #pragma unroll
    for (int ti = 0; ti < 2; ++ti) {
        #pragma unroll
        for (int tj = 0; tj < 2; ++tj) {
            int col = blockN + wc * 32 + tj * 16 + l15;
            float bv = bias ? bias[col] : 0.f;
            int row0 = blockM + wr * 32 + ti * 16 + quad * 4;
            #pragma unroll
            for (int r = 0; r < 4; ++r) {
                int m = row0 + r;
                float x = acc[ti][tj][r] + bv;
                if (relu) x = x > 0.f ? x : 0.f;
                int orow = rowmap ? (((m & 2047) << 2) | (m >> 11)) : m;
                C[(size_t)orow * ldc + col + colofs] = to_bf16s(x);
            }
        }
    }
}

// ---------------------------------------------------------------------------
// gemm128: m97-style 128x128 tile, BK=64, global_load_lds 16B, 2-barrier loop.
// A [M][K] bf16 (lda), B [N][K] bf16 (ldb), K chunk = blockIdx.z.
// MODE 1: adj partials -> big:  C[(m*4 + j>>7)*ldc + (j&127) + z*128] (bf16)
// MODE 2: mlp1: fp32 out, row (n*4+b) -> b*2048+n, +bias[col]
// ---------------------------------------------------------------------------
template <int MODE>
__global__ __launch_bounds__(256) void gemm128(
    const short* __restrict__ A, int lda,
    const short* __restrict__ B, int ldb,
    int kChunkIters, const float* __restrict__ bias,
    void* __restrict__ Cv, int ldc) {
    __shared__ __align__(16) short As[128 * 64];
    __shared__ __align__(16) short Bs[128 * 64];

    int tid = threadIdx.x;
    int blockM = blockIdx.x * 128;
    int blockN = blockIdx.y * 128;
    int kz = blockIdx.z * kChunkIters * 64;

    const short* Ab = A + (size_t)(blockM + (tid >> 3)) * lda + kz + (tid & 7) * 8;
    const short* Bb = B + (size_t)(blockN + (tid >> 3)) * ldb + kz + (tid & 7) * 8;
    short* Al = As + tid * 8;
    short* Bl = Bs + tid * 8;

    floatx4 acc[4][4];
    #pragma unroll
    for (int i = 0; i < 4; ++i)
        #pragma unroll
        for (int j = 0; j < 4; ++j)
            #pragma unroll
            for (int r = 0; r < 4; ++r) acc[i][j][r] = 0.f;

    int lane = tid & 63;
    int w = tid >> 6;
    int wr = w >> 1, wc = w & 1;
    int quad = lane >> 4, l15 = lane & 15;

    for (int it = 0; it < kChunkIters; ++it) {
        const short* Ag = Ab + it * 64;
        const short* Bg = Bb + it * 64;
        #pragma unroll
        for (int r = 0; r < 4; ++r) {
            dma16(Ag + (size_t)r * 32 * lda, Al + r * 2048);
            dma16(Bg + (size_t)r * 32 * ldb, Bl + r * 2048);
        }
        __syncthreads();  // drains vmcnt -> DMA data visible
        const short* Ar = As + (wr * 64 + l15) * 64;
        const short* Br = Bs + (wc * 64 + l15) * 64;
        #pragma unroll
        for (int ks = 0; ks < 2; ++ks) {
            int kof = ks * 32 + quad * 8;
            short8 af[4], bfr[4];
            #pragma unroll
            for (int i = 0; i < 4; ++i) af[i] = *(const short8*)(Ar + i * 16 * 64 + kof);
            #pragma unroll
            for (int j = 0; j < 4; ++j) bfr[j] = *(const short8*)(Br + j * 16 * 64 + kof);
            #pragma unroll
            for (int i = 0; i < 4; ++i)
                #pragma unroll
                for (int j = 0; j < 4; ++j)
                    acc[i][j] = __builtin_amdgcn_mfma_f32_16x16x32_bf16(af[i], bfr[j], acc[i][j], 0, 0, 0);
        }
        __syncthreads();  // before next iter's DMA overwrite
    }

    if (MODE == 1) {
        short* Cb = (short*)Cv;
        int colofs = blockIdx.z * 128;
        #pragma unroll
        for (int ti = 0; ti < 4; ++ti) {
            #pragma unroll
            for (int tj = 0; tj < 4; ++tj) {
                int j = blockN + wc * 64 + tj * 16 + l15;  // 0..511 = b*128+d
                int jhi = j >> 7, jlo = j & 127;
                int row0 = blockM + wr * 64 + ti * 16 + quad * 4;
                #pragma unroll
                for (int r = 0; r < 4; ++r) {
                    int m = row0 + r;  // node n
                    Cb[(size_t)(m * 4 + jhi) * ldc + jlo + colofs] = to_bf16s(acc[ti][tj][r]);
                }
            }
        }
    } else {
        float* Cf = (float*)Cv;
        #pragma unroll
        for (int ti = 0; ti < 4; ++ti) {
            #pragma unroll
            for (int tj = 0; tj < 4; ++tj) {
                int col = blockN + wc * 64 + tj * 16 + l15;
                float bv = bias[col];
                int row0 = blockM + wr * 64 + ti * 16 + quad * 4;
                #pragma unroll
                for (int r = 0; r < 4; ++r) {
                    int mp = row0 + r;  // n*4+b
                    int orow = ((mp & 3) << 11) | (mp >> 2);
                    Cf[(size_t)orow * ldc + col] = acc[ti][tj][r] + bv;
                }
            }
        }
    }
}

// ---------------------------------------------------------------------------
// Launch
// ---------------------------------------------------------------------------
extern "C" void kernel_launch(void* const* d_in, const int* in_sizes, int n_in,
                              void* d_out, int out_size, void* d_ws, size_t ws_size,
                              hipStream_t stream) {
    const float* x      = (const float*)d_in[0];
    const float* adj    = (const float*)d_in[1];
    const float* W_mlp2 = (const float*)d_in[2];
    const float* b_mlp2 = (const float*)d_in[3];
    const float* Wr1    = (const float*)d_in[4];
    const float* Wo1    = (const float*)d_in[5];
    const float* b1     = (const float*)d_in[6];
    const float* Wr2    = (const float*)d_in[7];
    const float* Wo2    = (const float*)d_in[8];
    const float* b2     = (const float*)d_in[9];
    const float* Wr3    = (const float*)d_in[10];
    const float* Wo3    = (const float*)d_in[11];
    const float* b3     = (const float*)d_in[12];
    const float* W_mlp1 = (const float*)d_in[13];
    const float* b_mlp1 = (const float*)d_in[14];
    float* out = (float*)d_out;

    char* ws = (char*)d_ws;
    size_t off = 0;
    auto alloc = [&](size_t bytes) -> char* {
        char* p = ws + off;
        off = (off + bytes + 255) & ~(size_t)255;
        return p;
    };
    short* W2T  = (short*)alloc(128 * 1536 * 2);
    short* W1T  = (short*)alloc(1536 * 128 * 2);
    short* BigB[3];
    for (int l = 0; l < 3; ++l) BigB[l] = (short*)alloc(128 * 640 * 2);
    short* adjS = (short*)alloc((size_t)2048 * 2048 * 2);
    short* big[4];
    for (int l = 0; l < 4; ++l) big[l] = (short*)alloc((size_t)8192 * 640 * 2);
    short* HT = (short*)alloc((size_t)512 * 2048 * 2);

    dim3 blk(256);

    PrepArgs pa{adj, W_mlp2, W_mlp1, Wr1, Wo1, Wr2, Wo2, Wr3, Wo3,
                adjS, W2T, W1T, BigB[0], BigB[1], BigB[2]};
    prep<<<2528, blk, 0, stream>>>(pa);

    // mlp2: big0[n*4+b][512+d] = x[b*2048+n] @ W2 + b2   (M=8192,K=1536,N=128)
    gemm64<float><<<dim3(128, 2), blk, 0, stream>>>(
        x, 1536, W2T, 1536, 24, b_mlp2, big[0], 640, 512, 0, 1);

    const float* biases[3] = {b1, b2, b3};
    for (int l = 0; l < 3; ++l) {
        // HT[b*128+d][n] = Hp_l
        transposeHp<<<dim3(4, 64, 4), blk, 0, stream>>>(big[l], HT);
        // big_l[:,0:512] = adjS @ Hp_l in 4 K-chunks  (M=2048,N=512,K=2048)
        gemm128<1><<<dim3(16, 4, 4), blk, 0, stream>>>(
            adjS, 2048, HT, 2048, 8, nullptr, big[l], 640);
        // Hp_{l+1} = relu(big_l @ BigB_l^T + b_l)    (M=8192,N=128,K=640)
        gemm64<short><<<dim3(128, 2), blk, 0, stream>>>(
            big[l], 640, BigB[l], 640, 10, biases[l], big[l + 1], 640, 512,
            (l < 2) ? 1 : 0, 0);
    }

    // mlp1: out[b*2048+n] = Hp3 @ W1 + b1   (M=8192,N=1536,K=128)
    gemm128<2><<<dim3(64, 12, 1), blk, 0, stream>>>(
        big[3] + 512, 640, W1T, 128, 2, b_mlp1, out, 1536);
}